// Round 2
// baseline (14872.652 us; speedup 1.0000x reference)
//
#include <hip/hip_runtime.h>
#include <cstddef>
#include <cstdint>
#include <math.h>

// B=64, T=512, V=50002, E=300, H=256, K=11, START=9, STOP=10
// Inputs: 0 sentence[B,T] i32, 1 batch_lengths, 2 emb[V,E], 3 fc_w[11,512], 4 fc_b[11],
//  5 transitions[11,11], 6..8 w_ih_l0f[1024,300]/w_hh_l0f[1024,256]/b_l0f,
//  9..11 l0b, 12..14 w_ih_l1f[1024,512]/w_hh_l1f/b_l1f, 15..17 l1b
// Output: [64 score][64*512 path] floats = 32832.

__device__ __forceinline__ float sigmf_(float x){ return 1.0f/(1.0f+expf(-x)); }

// ---------------- gather embeddings into zero-padded X [C*512, 304] ----------------
__global__ void k_gather(const int* __restrict__ sent, const float* __restrict__ emb,
                         float4* __restrict__ X, int total){
  int idx = blockIdx.x*256 + threadIdx.x;          // over C*512*76 float4s
  if (idx >= total) return;
  int m = idx / 76, k4 = idx - m*76;
  float4 v = make_float4(0.f,0.f,0.f,0.f);
  if (k4 < 75) v = ((const float4*)emb)[(size_t)sent[m]*75 + k4];   // E=300 -> 75 float4
  X[idx] = v;
}

// ------------- transpose w_ih (both dirs) into wT [dinPad, 2048]; concat bias -------------
__global__ void k_prepw(const float* __restrict__ wf, const float* __restrict__ wb,
                        const float* __restrict__ bf, const float* __restrict__ bb,
                        float* __restrict__ wT, float* __restrict__ bias,
                        int din, int dinPad){
  int total = dinPad*2048;
  for (int idx = blockIdx.x*blockDim.x + threadIdx.x; idx < total; idx += gridDim.x*blockDim.x){
    int k = idx >> 11, n = idx & 2047;
    float v = 0.f;
    if (k < din) v = (n < 1024) ? wf[n*din + k] : wb[(n-1024)*din + k];
    wT[idx] = v;
    if (idx < 2048) bias[idx] = (idx < 1024) ? bf[idx] : bb[idx-1024];
  }
}

__global__ void k_init(int* __restrict__ flags){
  if (threadIdx.x < 256) flags[threadIdx.x] = 0;
}

// ---------------- fp32 GEMM: C[M,2048] = A[M,lda] @ Bm[K,2048] + bias ----------------
// 128x128 tile per 256-thread block, 8x8 per thread, BK=16. M = gridDim.y*128.
__global__ __launch_bounds__(256) void k_gemm(const float* __restrict__ A, int lda, int kTiles,
                        const float* __restrict__ Bm, const float* __restrict__ bias,
                        float* __restrict__ C){
  __shared__ float As[16][132];
  __shared__ float Bs[16][132];
  const int t  = threadIdx.x;
  const int tx = t & 15, ty = t >> 4;
  const int m0 = blockIdx.y * 128, n0 = blockIdx.x * 128;
  const int arow = t >> 2, ak = (t & 3) * 4;     // A tile: 128 rows x 16 k
  const int brow = t >> 5, bc = (t & 31) * 4;    // B tile: 16 k x 128 cols
  float acc[8][8] = {};
  const float* Ap = A + (size_t)m0 * lda;
  for (int kt = 0; kt < kTiles; ++kt){
    const int kb = kt * 16;
    float4 a0 = *(const float4*)(Ap + (size_t)arow*lda + kb + ak);
    float4 a1 = *(const float4*)(Ap + (size_t)(arow+64)*lda + kb + ak);
    float4 b0 = *(const float4*)(Bm + (size_t)(kb+brow)*2048 + n0 + bc);
    float4 b1 = *(const float4*)(Bm + (size_t)(kb+brow+8)*2048 + n0 + bc);
    __syncthreads();
    As[ak+0][arow] = a0.x; As[ak+1][arow] = a0.y; As[ak+2][arow] = a0.z; As[ak+3][arow] = a0.w;
    As[ak+0][arow+64] = a1.x; As[ak+1][arow+64] = a1.y; As[ak+2][arow+64] = a1.z; As[ak+3][arow+64] = a1.w;
    *(float4*)&Bs[brow  ][bc] = b0;
    *(float4*)&Bs[brow+8][bc] = b1;
    __syncthreads();
    #pragma unroll
    for (int k = 0; k < 16; ++k){
      float av[8], bv[8];
      *(float4*)&av[0] = *(const float4*)&As[k][ty*8];
      *(float4*)&av[4] = *(const float4*)&As[k][ty*8+4];
      *(float4*)&bv[0] = *(const float4*)&Bs[k][tx*8];
      *(float4*)&bv[4] = *(const float4*)&Bs[k][tx*8+4];
      #pragma unroll
      for (int i = 0; i < 8; ++i)
        #pragma unroll
        for (int jj = 0; jj < 8; ++jj)
          acc[i][jj] = fmaf(av[i], bv[jj], acc[i][jj]);
    }
  }
  float bvals[8];
  *(float4*)&bvals[0] = *(const float4*)(bias + n0 + tx*8);
  *(float4*)&bvals[4] = *(const float4*)(bias + n0 + tx*8 + 4);
  float* Cp = C + (size_t)(m0 + ty*8)*2048 + n0 + tx*8;
  #pragma unroll
  for (int i = 0; i < 8; ++i){
    float4 o0 = make_float4(acc[i][0]+bvals[0], acc[i][1]+bvals[1], acc[i][2]+bvals[2], acc[i][3]+bvals[3]);
    float4 o1 = make_float4(acc[i][4]+bvals[4], acc[i][5]+bvals[5], acc[i][6]+bvals[6], acc[i][7]+bvals[7]);
    *(float4*)(Cp + (size_t)i*2048)     = o0;
    *(float4*)(Cp + (size_t)i*2048 + 4) = o1;
  }
}

// ---------------- LSTM recurrence: 2 blocks per (batch,dir) chain ----------------
// Block = (chain, half hh). 512 threads own 512 gate rows (i,f,g,o x 128 h-indices of
// this half) as 2 half-rows x 128 k in VGPRs (256 regs). h broadcast via LDS;
// h-half exchange between partner blocks via global hx + parity slots + agent-scope
// release/acquire flags. Launched cooperatively (partner co-residency guaranteed).
__global__ __launch_bounds__(512, 2) void k_lstm2(
    const float* __restrict__ xw, const float* __restrict__ whhf,
    const float* __restrict__ whhb, float* __restrict__ hout,
    float* __restrict__ hx, int* __restrict__ flags, int epoch)
{
  const int blk = blockIdx.x;
  const int chain = blk >> 1;          // local chain = b_local*2 + dir
  const int hh = blk & 1;
  const int b_local = chain >> 1;
  const int dir = chain & 1;
  const int t = threadIdx.x;
  const int wv = t >> 6, lane = t & 63;
  const int kap = lane >> 5, li = lane & 31;
  const int r0 = wv*64 + li*2;         // block-local rows r0, r0+1 (same gate: r0 even)
  const int rK = r0 + kap;             // the row this thread finalizes
  const int gateK = rK >> 7;
  float4 w0[32], w1[32];
  {
    const float* whh = dir ? whhb : whhf;
    const int g0 = r0 >> 7, i0 = r0 & 127;
    const float4* a = (const float4*)(whh + (size_t)(g0*256 + hh*128 + i0)*256 + kap*128);
    const float4* b = (const float4*)(whh + (size_t)(g0*256 + hh*128 + i0 + 1)*256 + kap*128);
    #pragma unroll
    for (int q = 0; q < 32; ++q){ w0[q] = a[q]; w1[q] = b[q]; }
  }
  __shared__ float hfull[256];
  __shared__ float gls[512];
  if (t < 256) hfull[t] = 0.f;
  float c = 0.f;
  const int xcol = dir*1024 + gateK*256 + hh*128 + (rK & 127);
  const float* xb = xw + (size_t)b_local*512*2048 + xcol;
  float* hxme        = hx + (size_t)(chain*2 + hh)*256;        // [parity][128]
  const float* hxpt  = hx + (size_t)(chain*2 + (1-hh))*256;
  int* flg  = flags + chain*2 + hh;
  int* flgp = flags + chain*2 + (1-hh);
  float* hob = hout + (size_t)b_local*512*512 + dir*256 + hh*128;
  __syncthreads();
  float xg = xb[(size_t)(dir ? 511 : 0)*2048];
  for (int s = 0; s < 512; ++s){
    const int tt = dir ? (511 - s) : s;
    float xn = 0.f;
    if (s < 511) xn = xb[(size_t)(dir ? (510 - s) : (s + 1))*2048];  // prefetch
    float p0 = 0.f, p1 = 0.f;
    const float4* h4 = ((const float4*)hfull) + kap*32;
    #pragma unroll
    for (int q = 0; q < 32; ++q){
      float4 hv = h4[q];                         // 32 lanes/addr -> LDS broadcast
      p0 = fmaf(w0[q].x, hv.x, p0);
      p1 = fmaf(w1[q].x, hv.x, p1);
      p0 = fmaf(w0[q].y, hv.y, p0);
      p1 = fmaf(w1[q].y, hv.y, p1);
      p0 = fmaf(w0[q].z, hv.z, p0);
      p1 = fmaf(w1[q].z, hv.z, p1);
      p0 = fmaf(w0[q].w, hv.w, p0);
      p1 = fmaf(w1[q].w, hv.w, p1);
    }
    float q0 = p0 + __shfl_xor(p0, 32, 64);      // combine k-halves (lane ^32 = same rows)
    float q1 = p1 + __shfl_xor(p1, 32, 64);
    float acc = (kap ? q1 : q0) + xg;
    float act = (gateK == 2) ? tanhf(acc) : sigmf_(acc);   // i,f,o sigmoid; g tanh
    gls[rK] = act;
    __syncthreads();                             // B1: gates ready
    if (t < 128){
      c = gls[128 + t]*c + gls[t]*gls[256 + t];  // c = sig(f)*c + sig(i)*tanh(g)
      float h = gls[384 + t]*tanhf(c);
      hfull[hh*128 + t] = h;
      hxme[(s & 1)*128 + t] = h;                 // publish data (parity double-buffer)
      hob[(size_t)tt*512 + t] = h;
    }
    __syncthreads();                             // B2: all stores drained (vmcnt 0/wave)
    if (t == 0){
      __hip_atomic_store(flg, epoch + s + 1, __ATOMIC_RELEASE, __HIP_MEMORY_SCOPE_AGENT);
      int lim = 0;                               // bounded spin (hang fuse)
      while (__hip_atomic_load(flgp, __ATOMIC_ACQUIRE, __HIP_MEMORY_SCOPE_AGENT) < epoch + s + 1
             && ++lim < 200000) {}
    }
    __syncthreads();                             // B3: partner data visible
    if (t < 128) hfull[(1 - hh)*128 + t] = hxpt[(s & 1)*128 + t];
    __syncthreads();                             // B4: hfull complete for next step
    xg = xn;
  }
}

// ---------------- emission scores: feats[m,11] = h1 @ fc_w^T + fc_b ----------------
__global__ __launch_bounds__(256) void k_feats(const float* __restrict__ h1, const float* __restrict__ fcw,
                        const float* __restrict__ fcb, float* __restrict__ feats, int base){
  int wave = threadIdx.x >> 6, lane = threadIdx.x & 63;
  int m = blockIdx.x*4 + wave;
  const float4* row = (const float4*)(h1 + (size_t)m*512);
  float4 r0 = row[lane*2], r1 = row[lane*2+1];
  #pragma unroll
  for (int n = 0; n < 11; ++n){
    const float4* wr = (const float4*)(fcw + n*512);
    float4 w0 = wr[lane*2], w1 = wr[lane*2+1];
    float p = r0.x*w0.x + r0.y*w0.y + r0.z*w0.z + r0.w*w0.w
            + r1.x*w1.x + r1.y*w1.y + r1.z*w1.z + r1.w*w1.w;
    #pragma unroll
    for (int off = 32; off > 0; off >>= 1) p += __shfl_down(p, off, 64);
    if (lane == 0) feats[((size_t)base*512 + m)*11 + n] = p + fcb[n];
  }
}

// ---------------- Viterbi: 1 wave per batch; backtrack by lane 0 ----------------
__global__ __launch_bounds__(256) void k_viterbi(const float* __restrict__ feats,
                        const float* __restrict__ trans, float* __restrict__ out){
  __shared__ unsigned char bp[4][512][12];
  const int wave = threadIdx.x >> 6, lane = threadIdx.x & 63;
  const int b = blockIdx.x*4 + wave;
  const int j = lane;                         // next-state for lanes < 11
  float tr[11];
  float fv;
  if (j < 11){
    #pragma unroll
    for (int p = 0; p < 11; ++p) tr[p] = trans[j*11 + p];
    fv = (j == 9) ? 0.f : -1000.f;            // START=9
  } else {
    #pragma unroll
    for (int p = 0; p < 11; ++p) tr[p] = -1e30f;
    fv = -1e30f;
  }
  for (int t = 0; t < 512; ++t){
    float best = -1e38f; int bestp = 0;
    #pragma unroll
    for (int p = 0; p < 11; ++p){
      float v = __shfl(fv, p, 64) + tr[p];
      if (v > best){ best = v; bestp = p; }   // strict > keeps FIRST max (np.argmax)
    }
    float feat = (j < 11) ? feats[((size_t)b*512 + t)*11 + j] : 0.f;
    fv = best + feat;
    if (j < 11) bp[wave][t][j] = (unsigned char)bestp;
  }
  float term = (j < 11) ? fv + trans[10*11 + j] : -1e38f;   // + transitions[STOP, prev]
  float best = -1e38f; int bestp = 0;
  #pragma unroll
  for (int p = 0; p < 11; ++p){
    float v = __shfl(term, p, 64);
    if (v > best){ best = v; bestp = p; }
  }
  if (lane == 0){
    out[b] = best;                            // path_score [B,1]
    float* path = out + 64 + (size_t)b*512;   // path (written as float)
    int cur = bestp;
    path[511] = (float)cur;
    for (int t = 511; t >= 1; --t){
      cur = bp[wave][t][cur];
      path[t-1] = (float)cur;
    }
  }
}

extern "C" void kernel_launch(void* const* d_in, const int* in_sizes, int n_in,
                              void* d_out, int out_size, void* d_ws, size_t ws_size,
                              hipStream_t stream){
  const int*   sent  = (const int*)d_in[0];
  const float* emb   = (const float*)d_in[2];
  const float* fcw   = (const float*)d_in[3];
  const float* fcb   = (const float*)d_in[4];
  const float* trans = (const float*)d_in[5];
  const float* wih0f = (const float*)d_in[6];
  const float* whh0f = (const float*)d_in[7];
  const float* b0f   = (const float*)d_in[8];
  const float* wih0b = (const float*)d_in[9];
  const float* whh0b = (const float*)d_in[10];
  const float* b0b   = (const float*)d_in[11];
  const float* wih1f = (const float*)d_in[12];
  const float* whh1f = (const float*)d_in[13];
  const float* b1f   = (const float*)d_in[14];
  const float* wih1b = (const float*)d_in[15];
  const float* whh1b = (const float*)d_in[16];
  const float* b1b   = (const float*)d_in[17];

  float* ws = (float*)d_ws;
  // -------- fixed region (floats) --------
  const size_t F_wT0  = 0;                                 // 304*2048
  const size_t F_wT1  = F_wT0 + (size_t)304*2048;          // 512*2048
  const size_t F_b0   = F_wT1 + (size_t)512*2048;          // 2048
  const size_t F_b1   = F_b0  + 2048;                      // 2048
  const size_t F_flag = F_b1  + 2048;                      // 1024 (256 ints used)
  const size_t F_hx   = F_flag + 1024;                     // 65536
  const size_t F_feat = F_hx   + 65536;                    // 32768*11 = 360448
  const size_t F_var  = F_feat + 360448;                   // = 2,102,272 floats fixed
  float* wT0   = ws + F_wT0;
  float* wT1   = ws + F_wT1;
  float* bias0 = ws + F_b0;
  float* bias1 = ws + F_b1;
  int*   flags = (int*)(ws + F_flag);
  float* hx    = ws + F_hx;
  float* feats = ws + F_feat;

  // -------- choose batch-chunk size C so everything fits in ws_size --------
  int C = 1;
  const int cands[7] = {64, 32, 16, 8, 4, 2, 1};
  for (int ci = 0; ci < 7; ++ci){
    int c = cands[ci];
    size_t needF = F_var + (size_t)c*512*(304 + 512 + 2048);
    if (needF*4 <= ws_size){ C = c; break; }
  }
  float* X   = ws + F_var;                     // [C*512, 304]
  float* hC  = X  + (size_t)C*512*304;         // [C*512, 512]
  float* xwC = hC + (size_t)C*512*512;         // [C*512, 2048]

  hipLaunchKernelGGL(k_prepw, dim3(512), dim3(256), 0, stream, wih0f, wih0b, b0f, b0b, wT0, bias0, 300, 304);
  hipLaunchKernelGGL(k_prepw, dim3(512), dim3(256), 0, stream, wih1f, wih1b, b1f, b1b, wT1, bias1, 512, 512);
  hipLaunchKernelGGL(k_init,  dim3(1), dim3(256), 0, stream, flags);

  int ep = 0;
  for (int base = 0; base < 64; base += C){
    const int* sentC = sent + (size_t)base*512;
    hipLaunchKernelGGL(k_gather, dim3(C*152), dim3(256), 0, stream, sentC, emb, (float4*)X, C*512*76);
    // layer 0
    hipLaunchKernelGGL(k_gemm, dim3(16, C*4), dim3(256), 0, stream, X, 304, 19, wT0, bias0, xwC);
    {
      const float *xwp = xwC, *wf = whh0f, *wb = whh0b;
      float *hp = hC, *hxp = hx; int *flp = flags; int epoch = (ep++)*512;
      void* args[] = {(void*)&xwp, (void*)&wf, (void*)&wb, (void*)&hp, (void*)&hxp, (void*)&flp, (void*)&epoch};
      hipLaunchCooperativeKernel((const void*)k_lstm2, dim3(C*4), dim3(512), args, 0, stream);
    }
    // layer 1
    hipLaunchKernelGGL(k_gemm, dim3(16, C*4), dim3(256), 0, stream, hC, 512, 32, wT1, bias1, xwC);
    {
      const float *xwp = xwC, *wf = whh1f, *wb = whh1b;
      float *hp = hC, *hxp = hx; int *flp = flags; int epoch = (ep++)*512;
      void* args[] = {(void*)&xwp, (void*)&wf, (void*)&wb, (void*)&hp, (void*)&hxp, (void*)&flp, (void*)&epoch};
      hipLaunchCooperativeKernel((const void*)k_lstm2, dim3(C*4), dim3(512), args, 0, stream);
    }
    hipLaunchKernelGGL(k_feats, dim3(C*128), dim3(256), 0, stream, hC, fcw, fcb, feats, base);
  }
  hipLaunchKernelGGL(k_viterbi, dim3(16), dim3(256), 0, stream, feats, trans, (float*)d_out);
}

// Round 5
// 12861.549 us; speedup vs baseline: 1.1564x; 1.1564x over previous
//
#include <hip/hip_runtime.h>
#include <cstddef>
#include <cstdint>
#include <math.h>

// B=64, T=512, V=50002, E=300, H=256, K=11, START=9, STOP=10
// Output: [64 score][64*512 path] floats = 32832.

__device__ __forceinline__ float sigmf_(float x){ return 1.0f/(1.0f+expf(-x)); }

// ---------------- generic zero ----------------
__global__ void k_zero(float* __restrict__ p, int n){
  for (int i = blockIdx.x*blockDim.x + threadIdx.x; i < n; i += gridDim.x*blockDim.x) p[i] = 0.f;
}

// ---------------- gather embeddings slab: X[C*T,304] zero-padded ----------------
__global__ void k_gather(const int* __restrict__ sent, const float* __restrict__ emb,
                         float4* __restrict__ X, int b0, int t0, int logT, int Tm1, int total){
  int idx = blockIdx.x*256 + threadIdx.x;
  if (idx >= total) return;
  int m = idx / 76, k4 = idx - m*76;
  int bl = m >> logT, t = m & Tm1;
  float4 v = make_float4(0.f,0.f,0.f,0.f);
  if (k4 < 75) v = ((const float4*)emb)[(size_t)sent[(size_t)(b0+bl)*512 + t0 + t]*75 + k4];
  X[idx] = v;
}

// ---------------- transpose w_ih into wT [dinPad,1024] ----------------
__global__ void k_prepw(const float* __restrict__ w, float* __restrict__ wT, int din, int dinPad){
  int total = dinPad*1024;
  for (int idx = blockIdx.x*blockDim.x + threadIdx.x; idx < total; idx += gridDim.x*blockDim.x){
    int k = idx >> 10, n = idx & 1023;
    wT[idx] = (k < din) ? w[n*din + k] : 0.f;
  }
}

// ------- dual fp32 GEMM (z=0/1): C[M,1024] = A[M(strided rows),lda] @ Bm[K,1024] + bias -------
__global__ __launch_bounds__(256) void k_gemm2(
    const float* __restrict__ A0, const float* __restrict__ A1, int lda, int kTiles,
    int aBstride, int sOff0, int sOff1, int logT, int Tm1,
    const float* __restrict__ B0, const float* __restrict__ B1,
    const float* __restrict__ bias0, const float* __restrict__ bias1,
    float* __restrict__ C0, float* __restrict__ C1){
  __shared__ float As[16][132];
  __shared__ float Bs[16][132];
  const int z = blockIdx.z;
  const float* A   = z ? A1 : A0;
  const float* Bm  = z ? B1 : B0;
  const float* bias= z ? bias1 : bias0;
  float* Cc        = z ? C1 : C0;
  const int sOff   = z ? sOff1 : sOff0;
  const int t  = threadIdx.x;
  const int tx = t & 15, ty = t >> 4;
  const int m0 = blockIdx.y * 128, n0 = blockIdx.x * 128;
  const int arow = t >> 2, ak = (t & 3) * 4;
  const int brow = t >> 5, bc = (t & 31) * 4;
  const int gm0 = m0 + arow, gm1 = m0 + arow + 64;
  const size_t r0 = (size_t)(gm0 >> logT)*aBstride + sOff + (gm0 & Tm1);
  const size_t r1 = (size_t)(gm1 >> logT)*aBstride + sOff + (gm1 & Tm1);
  float acc[8][8] = {};
  for (int kt = 0; kt < kTiles; ++kt){
    const int kb = kt * 16;
    float4 a0 = *(const float4*)(A + r0*lda + kb + ak);
    float4 a1 = *(const float4*)(A + r1*lda + kb + ak);
    float4 b0 = *(const float4*)(Bm + (size_t)(kb+brow)*1024 + n0 + bc);
    float4 b1 = *(const float4*)(Bm + (size_t)(kb+brow+8)*1024 + n0 + bc);
    __syncthreads();
    As[ak+0][arow] = a0.x; As[ak+1][arow] = a0.y; As[ak+2][arow] = a0.z; As[ak+3][arow] = a0.w;
    As[ak+0][arow+64] = a1.x; As[ak+1][arow+64] = a1.y; As[ak+2][arow+64] = a1.z; As[ak+3][arow+64] = a1.w;
    *(float4*)&Bs[brow  ][bc] = b0;
    *(float4*)&Bs[brow+8][bc] = b1;
    __syncthreads();
    #pragma unroll
    for (int k = 0; k < 16; ++k){
      float av[8], bv[8];
      *(float4*)&av[0] = *(const float4*)&As[k][ty*8];
      *(float4*)&av[4] = *(const float4*)&As[k][ty*8+4];
      *(float4*)&bv[0] = *(const float4*)&Bs[k][tx*8];
      *(float4*)&bv[4] = *(const float4*)&Bs[k][tx*8+4];
      #pragma unroll
      for (int i = 0; i < 8; ++i)
        #pragma unroll
        for (int jj = 0; jj < 8; ++jj)
          acc[i][jj] = fmaf(av[i], bv[jj], acc[i][jj]);
    }
  }
  float bvals[8];
  *(float4*)&bvals[0] = *(const float4*)(bias + n0 + tx*8);
  *(float4*)&bvals[4] = *(const float4*)(bias + n0 + tx*8 + 4);
  float* Cp = Cc + (size_t)(m0 + ty*8)*1024 + n0 + tx*8;
  #pragma unroll
  for (int i = 0; i < 8; ++i){
    float4 o0 = make_float4(acc[i][0]+bvals[0], acc[i][1]+bvals[1], acc[i][2]+bvals[2], acc[i][3]+bvals[3]);
    float4 o1 = make_float4(acc[i][4]+bvals[4], acc[i][5]+bvals[5], acc[i][6]+bvals[6], acc[i][7]+bvals[7]);
    *(float4*)(Cp + (size_t)i*1024)     = o0;
    *(float4*)(Cp + (size_t)i*1024 + 4) = o1;
  }
}

// ---------------- LSTM recurrence: R2's bit-exact kernel, slab-adapted ----------------
// 2 blocks per (batch,dir) chain; 512 threads own 512 gate rows as 2 half-rows x 128 k
// in VGPRs (256 regs, launch_bounds(512,1) so they DON'T spill). h broadcast via LDS;
// h-half exchange via global hx + parity slots + agent-scope flags (verified R2).
// Slab plumbing: xwF/xwB split inputs, h/c save-restore across launches.
__global__ __launch_bounds__(512, 1) void k_lstm2s(
    const float* __restrict__ xwF, const float* __restrict__ xwB,
    const float* __restrict__ whhf, const float* __restrict__ whhb,
    float* __restrict__ hout, int hBstride, int tOffF, int tOffB,
    int T, int epoch,
    float* __restrict__ hx, int* __restrict__ flags,
    float* __restrict__ hsave, float* __restrict__ csave)
{
  const int blk = blockIdx.x;
  const int chain = blk >> 1;          // chain = b_local*2 + dir
  const int hh = blk & 1;
  const int b_local = chain >> 1;
  const int dir = chain & 1;
  const int t = threadIdx.x;
  const int wv = t >> 6, lane = t & 63;
  const int kap = lane >> 5, li = lane & 31;
  const int r0 = wv*64 + li*2;         // block-local rows r0, r0+1
  const int rK = r0 + kap;             // row this thread finalizes
  const int gateK = rK >> 7;
  float4 w0[32], w1[32];
  {
    const float* whh = dir ? whhb : whhf;
    const int g0 = r0 >> 7, i0 = r0 & 127;
    const float4* a = (const float4*)(whh + (size_t)(g0*256 + hh*128 + i0)*256 + kap*128);
    const float4* b = (const float4*)(whh + (size_t)(g0*256 + hh*128 + i0 + 1)*256 + kap*128);
    #pragma unroll
    for (int q = 0; q < 32; ++q){ w0[q] = a[q]; w1[q] = b[q]; }
  }
  __shared__ float hfull[256];
  __shared__ float gls[512];
  if (t < 256) hfull[t] = hsave[chain*256 + t];
  float c = (t < 128) ? csave[chain*256 + hh*128 + t] : 0.f;
  __syncthreads();
  const int xcol = gateK*256 + hh*128 + (rK & 127);
  const float* xb = (dir ? xwB : xwF) + (size_t)b_local*T*1024 + xcol;
  float* hxme        = hx + (size_t)(chain*2 + hh)*256;        // [parity][128]
  const float* hxpt  = hx + (size_t)(chain*2 + (1-hh))*256;
  int* flg  = flags + chain*2 + hh;
  int* flgp = flags + chain*2 + (1-hh);
  const int tOff = dir ? tOffB : tOffF;
  float* hob = hout + (size_t)b_local*hBstride + dir*256 + hh*128;
  float xg = xb[(size_t)(dir ? (T-1) : 0)*1024];
  for (int s = 0; s < T; ++s){
    const int tt = dir ? (T-1-s) : s;
    float xn = 0.f;
    if (s < T-1) xn = xb[(size_t)(dir ? (T-2-s) : (s+1))*1024];   // prefetch
    float p0 = 0.f, p1 = 0.f;
    const float4* h4 = ((const float4*)hfull) + kap*32;
    #pragma unroll
    for (int q = 0; q < 32; ++q){
      float4 hv = h4[q];                        // wave-uniform addr -> LDS broadcast
      p0 = fmaf(w0[q].x, hv.x, p0);  p1 = fmaf(w1[q].x, hv.x, p1);
      p0 = fmaf(w0[q].y, hv.y, p0);  p1 = fmaf(w1[q].y, hv.y, p1);
      p0 = fmaf(w0[q].z, hv.z, p0);  p1 = fmaf(w1[q].z, hv.z, p1);
      p0 = fmaf(w0[q].w, hv.w, p0);  p1 = fmaf(w1[q].w, hv.w, p1);
    }
    float q0 = p0 + __shfl_xor(p0, 32, 64);     // combine k-halves
    float q1 = p1 + __shfl_xor(p1, 32, 64);
    float acc = (kap ? q1 : q0) + xg;
    float act = (gateK == 2) ? tanhf(acc) : sigmf_(acc);   // i,f,o sigmoid; g tanh
    gls[rK] = act;
    __syncthreads();                            // B1: gates ready
    if (t < 128){
      c = gls[128 + t]*c + gls[t]*gls[256 + t];
      float h = gls[384 + t]*tanhf(c);
      hfull[hh*128 + t] = h;
      hxme[(s & 1)*128 + t] = h;                // publish (parity dbuf)
      hob[(size_t)(tOff + tt)*512 + t] = h;
    }
    __syncthreads();                            // B2: stores drained
    if (t == 0){
      __hip_atomic_store(flg, epoch + s + 1, __ATOMIC_RELEASE, __HIP_MEMORY_SCOPE_AGENT);
      int lim = 0;                              // bounded spin (hang fuse)
      while (__hip_atomic_load(flgp, __ATOMIC_ACQUIRE, __HIP_MEMORY_SCOPE_AGENT) < epoch + s + 1
             && ++lim < (1<<20)) {}
    }
    __syncthreads();                            // B3: partner data visible
    if (t < 128) hfull[(1 - hh)*128 + t] = hxpt[(s & 1)*128 + t];
    __syncthreads();                            // B4: hfull ready for next step
    xg = xn;
  }
  if (t < 128){
    hsave[chain*256 + hh*128 + t] = hfull[hh*128 + t];
    csave[chain*256 + hh*128 + t] = c;
  }
}

// ---------------- feats accumulation (one dir half per call) ----------------
__global__ __launch_bounds__(256) void k_feats_half(
    const float* __restrict__ h1s, const float* __restrict__ fcw, const float* __restrict__ fcb,
    float* __restrict__ feats, int b0, int logT, int Tm1, int tG0, int dir){
  int wv = threadIdx.x >> 6, lane = threadIdx.x & 63;
  int m = blockIdx.x*4 + wv;                 // m = bl*T + tl
  const float4* row = (const float4*)(h1s + (size_t)m*512 + dir*256);
  float4 rv = row[lane];
  int bl = m >> logT, tl = m & Tm1;
  size_t fbase = ((size_t)(b0 + bl)*512 + tG0 + tl)*11;
  #pragma unroll
  for (int n = 0; n < 11; ++n){
    const float4* wr = (const float4*)(fcw + n*512 + dir*256);
    float4 w4 = wr[lane];
    float p = rv.x*w4.x + rv.y*w4.y + rv.z*w4.z + rv.w*w4.w;
    #pragma unroll
    for (int off = 32; off > 0; off >>= 1) p += __shfl_down(p, off, 64);
    if (lane == 0){
      float add = (dir == 0) ? (p + fcb[n]) : p;
      feats[fbase + n] += add;
    }
  }
}

// ---------------- Viterbi: 1 wave per batch (verified R2) ----------------
__global__ __launch_bounds__(256) void k_viterbi(const float* __restrict__ feats,
                        const float* __restrict__ trans, float* __restrict__ out){
  __shared__ unsigned char bp[4][512][12];
  const int wave = threadIdx.x >> 6, lane = threadIdx.x & 63;
  const int b = blockIdx.x*4 + wave;
  const int j = lane;
  float tr[11];
  float fv;
  if (j < 11){
    #pragma unroll
    for (int p = 0; p < 11; ++p) tr[p] = trans[j*11 + p];
    fv = (j == 9) ? 0.f : -1000.f;
  } else {
    #pragma unroll
    for (int p = 0; p < 11; ++p) tr[p] = -1e30f;
    fv = -1e30f;
  }
  for (int t = 0; t < 512; ++t){
    float best = -1e38f; int bestp = 0;
    #pragma unroll
    for (int p = 0; p < 11; ++p){
      float v = __shfl(fv, p, 64) + tr[p];
      if (v > best){ best = v; bestp = p; }   // strict > keeps FIRST max (np.argmax)
    }
    float feat = (j < 11) ? feats[((size_t)b*512 + t)*11 + j] : 0.f;
    fv = best + feat;
    if (j < 11) bp[wave][t][j] = (unsigned char)bestp;
  }
  float term = (j < 11) ? fv + trans[10*11 + j] : -1e38f;
  float best = -1e38f; int bestp = 0;
  #pragma unroll
  for (int p = 0; p < 11; ++p){
    float v = __shfl(term, p, 64);
    if (v > best){ best = v; bestp = p; }
  }
  if (lane == 0){
    out[b] = best;
    float* path = out + 64 + (size_t)b*512;
    int cur = bestp;
    path[511] = (float)cur;
    for (int t = 511; t >= 1; --t){
      cur = bp[wave][t][cur];
      path[t-1] = (float)cur;
    }
  }
}

extern "C" void kernel_launch(void* const* d_in, const int* in_sizes, int n_in,
                              void* d_out, int out_size, void* d_ws, size_t ws_size,
                              hipStream_t stream){
  const int*   sent  = (const int*)d_in[0];
  const float* emb   = (const float*)d_in[2];
  const float* fcw   = (const float*)d_in[3];
  const float* fcb   = (const float*)d_in[4];
  const float* trans = (const float*)d_in[5];
  const float* wih0f = (const float*)d_in[6];
  const float* whh0f = (const float*)d_in[7];
  const float* b0f   = (const float*)d_in[8];
  const float* wih0b = (const float*)d_in[9];
  const float* whh0b = (const float*)d_in[10];
  const float* b0b   = (const float*)d_in[11];
  const float* wih1f = (const float*)d_in[12];
  const float* whh1f = (const float*)d_in[13];
  const float* b1f   = (const float*)d_in[14];
  const float* wih1b = (const float*)d_in[15];
  const float* whh1b = (const float*)d_in[16];
  const float* b1b   = (const float*)d_in[17];

  float* ws = (float*)d_ws;
  // -------- fixed region (float offsets) --------
  const size_t o_wT0f = 0;                         // 304*1024
  const size_t o_wT0b = o_wT0f + 311296;
  const size_t o_wT1f = o_wT0b + 311296;           // 512*1024
  const size_t o_wT1b = o_wT1f + 524288;
  const size_t o_hx   = o_wT1b + 524288;           // 64*2 chains * 2 hh * 2 par * 128 = 65536
  const size_t o_flag = o_hx   + 65536;            // 256 ints
  const size_t o_hs   = o_flag + 256;              // hsave 128 chains * 256 = 32768
  const size_t o_cs   = o_hs   + 32768;            // csave 32768
  const size_t o_feat = o_cs   + 32768;            // 32768*11 = 360448
  const size_t o_var  = o_feat + 360448;           // = 2,162,944 floats fixed (8.65 MB)
  float* wT0f = ws + o_wT0f;
  float* wT0b = ws + o_wT0b;
  float* wT1f = ws + o_wT1f;
  float* wT1b = ws + o_wT1b;
  float* hx    = ws + o_hx;
  int*   flags = (int*)(ws + o_flag);
  float* hsave = ws + o_hs;
  float* csave = ws + o_cs;
  float* feats = ws + o_feat;

  // -------- adaptive (C batches, T timesteps) slab sizing --------
  int C = 8, T = 32, logT = 5;
  {
    const int cc[7]  = {64, 64, 32, 32, 16, 16, 8};
    const int tt[7]  = {32, 16, 32, 16, 32, 16, 32};
    const int lt[7]  = { 5,  4,  5,  4,  5,  4,  5};
    for (int i = 0; i < 7; ++i){
      size_t need = (o_var + (size_t)cc[i]*tt[i]*2656 + (size_t)cc[i]*262144)*4;
      if (need <= ws_size){ C = cc[i]; T = tt[i]; logT = lt[i]; break; }
    }
  }
  const int Tm1 = T - 1, S = 512 / T;
  float* XF  = ws + o_var;                        // [C*T,304]  (layer0)
  float* XB  = XF + (size_t)C*T*304;
  float* xwF = XB + (size_t)C*T*304;              // [C*T,1024]
  float* xwB = xwF + (size_t)C*T*1024;
  float* h0  = xwB + (size_t)C*T*1024;            // [C,512,512] fp32
  float* h1s = XF;                                // alias: [C,T,512] (layer1 slab)

  hipLaunchKernelGGL(k_prepw, dim3(512), dim3(256), 0, stream, wih0f, wT0f, 300, 304);
  hipLaunchKernelGGL(k_prepw, dim3(512), dim3(256), 0, stream, wih0b, wT0b, 300, 304);
  hipLaunchKernelGGL(k_prepw, dim3(512), dim3(256), 0, stream, wih1f, wT1f, 512, 512);
  hipLaunchKernelGGL(k_prepw, dim3(512), dim3(256), 0, stream, wih1b, wT1b, 512, 512);
  hipLaunchKernelGGL(k_zero,  dim3(512), dim3(256), 0, stream, feats, 360448);

  for (int b0 = 0; b0 < 64; b0 += C){
    for (int layer = 0; layer < 2; ++layer){
      // zero flags + hsave + csave (contiguous region)
      hipLaunchKernelGGL(k_zero, dim3(128), dim3(256), 0, stream, ws + o_flag, 256 + 65536);
      const float* whF = layer ? whh1f : whh0f;
      const float* whB = layer ? whh1b : whh0b;
      for (int sl = 0; sl < S; ++sl){
        const int sF = sl, sB = S - 1 - sl;
        const int M = C*T;
        if (layer == 0){
          int total = C*T*76;
          hipLaunchKernelGGL(k_gather, dim3((total+255)/256), dim3(256), 0, stream,
                             sent, emb, (float4*)XF, b0, sF*T, logT, Tm1, total);
          hipLaunchKernelGGL(k_gather, dim3((total+255)/256), dim3(256), 0, stream,
                             sent, emb, (float4*)XB, b0, sB*T, logT, Tm1, total);
          hipLaunchKernelGGL(k_gemm2, dim3(8, M/128, 2), dim3(256), 0, stream,
                             XF, XB, 304, 19, T, 0, 0, logT, Tm1,
                             wT0f, wT0b, b0f, b0b, xwF, xwB);
        } else {
          hipLaunchKernelGGL(k_gemm2, dim3(8, M/128, 2), dim3(256), 0, stream,
                             h0, h0, 512, 32, 512, sF*T, sB*T, logT, Tm1,
                             wT1f, wT1b, b1f, b1b, xwF, xwB);
        }
        {
          const float *xF = xwF, *xB = xwB, *wF = whF, *wB = whB;
          float* hop = layer ? h1s : h0;
          int hBs  = layer ? T*512 : 512*512;
          int tOF  = layer ? 0 : sF*T;
          int tOB  = layer ? 0 : sB*T;
          int Tk = T, ep = sl*T;
          float *hxp = hx, *hsp = hsave, *csp = csave; int *flp = flags;
          void* args[] = {(void*)&xF, (void*)&xB, (void*)&wF, (void*)&wB,
                          (void*)&hop, (void*)&hBs, (void*)&tOF, (void*)&tOB,
                          (void*)&Tk, (void*)&ep,
                          (void*)&hxp, (void*)&flp, (void*)&hsp, (void*)&csp};
          hipLaunchCooperativeKernel((const void*)k_lstm2s, dim3(C*4), dim3(512), args, 0, stream);
        }
        if (layer == 1){
          hipLaunchKernelGGL(k_feats_half, dim3(C*T/4), dim3(256), 0, stream,
                             h1s, fcw, fcb, feats, b0, logT, Tm1, sF*T, 0);
          hipLaunchKernelGGL(k_feats_half, dim3(C*T/4), dim3(256), 0, stream,
                             h1s, fcw, fcb, feats, b0, logT, Tm1, sB*T, 1);
        }
      }
    }
  }
  hipLaunchKernelGGL(k_viterbi, dim3(16), dim3(256), 0, stream, feats, trans, (float*)d_out);
}

// Round 8
// 10987.039 us; speedup vs baseline: 1.3537x; 1.1706x over previous
//
#include <hip/hip_runtime.h>
#include <cstddef>
#include <cstdint>
#include <math.h>

// B=64, T=512, V=50002, E=300, H=256, K=11, START=9, STOP=10
// Output: [64 score][64*512 path] floats = 32832.

__device__ __forceinline__ float sigmf_(float x){ return 1.0f/(1.0f+expf(-x)); }

// ---------------- generic zero ----------------
__global__ void k_zero(float* __restrict__ p, int n){
  for (int i = blockIdx.x*blockDim.x + threadIdx.x; i < n; i += gridDim.x*blockDim.x) p[i] = 0.f;
}

// ---------------- gather embeddings slab: X[C*T,304] zero-padded ----------------
__global__ void k_gather(const int* __restrict__ sent, const float* __restrict__ emb,
                         float4* __restrict__ X, int b0, int t0, int logT, int Tm1, int total){
  int idx = blockIdx.x*256 + threadIdx.x;
  if (idx >= total) return;
  int m = idx / 76, k4 = idx - m*76;
  int bl = m >> logT, t = m & Tm1;
  float4 v = make_float4(0.f,0.f,0.f,0.f);
  if (k4 < 75) v = ((const float4*)emb)[(size_t)sent[(size_t)(b0+bl)*512 + t0 + t]*75 + k4];
  X[idx] = v;
}

// ---------------- transpose w_ih into wT [dinPad,1024] (R5-proven) ----------------
__global__ void k_prepw(const float* __restrict__ w, float* __restrict__ wT, int din, int dinPad){
  int total = dinPad*1024;
  for (int idx = blockIdx.x*blockDim.x + threadIdx.x; idx < total; idx += gridDim.x*blockDim.x){
    int k = idx >> 10, n = idx & 1023;
    wT[idx] = (k < din) ? w[n*din + k] : 0.f;
  }
}

// ------- dual fp32 GEMM (z=0/1): C[M,1024] = A[M(strided rows),lda] @ Bm[K,1024] + bias -------
// (byte-identical to R5's proven k_gemm2)
__global__ __launch_bounds__(256) void k_gemm2(
    const float* __restrict__ A0, const float* __restrict__ A1, int lda, int kTiles,
    int aBstride, int sOff0, int sOff1, int logT, int Tm1,
    const float* __restrict__ B0, const float* __restrict__ B1,
    const float* __restrict__ bias0, const float* __restrict__ bias1,
    float* __restrict__ C0, float* __restrict__ C1){
  __shared__ float As[16][132];
  __shared__ float Bs[16][132];
  const int z = blockIdx.z;
  const float* A   = z ? A1 : A0;
  const float* Bm  = z ? B1 : B0;
  const float* bias= z ? bias1 : bias0;
  float* Cc        = z ? C1 : C0;
  const int sOff   = z ? sOff1 : sOff0;
  const int t  = threadIdx.x;
  const int tx = t & 15, ty = t >> 4;
  const int m0 = blockIdx.y * 128, n0 = blockIdx.x * 128;
  const int arow = t >> 2, ak = (t & 3) * 4;
  const int brow = t >> 5, bc = (t & 31) * 4;
  const int gm0 = m0 + arow, gm1 = m0 + arow + 64;
  const size_t r0 = (size_t)(gm0 >> logT)*aBstride + sOff + (gm0 & Tm1);
  const size_t r1 = (size_t)(gm1 >> logT)*aBstride + sOff + (gm1 & Tm1);
  float acc[8][8] = {};
  for (int kt = 0; kt < kTiles; ++kt){
    const int kb = kt * 16;
    float4 a0 = *(const float4*)(A + r0*lda + kb + ak);
    float4 a1 = *(const float4*)(A + r1*lda + kb + ak);
    float4 b0 = *(const float4*)(Bm + (size_t)(kb+brow)*1024 + n0 + bc);
    float4 b1 = *(const float4*)(Bm + (size_t)(kb+brow+8)*1024 + n0 + bc);
    __syncthreads();
    As[ak+0][arow] = a0.x; As[ak+1][arow] = a0.y; As[ak+2][arow] = a0.z; As[ak+3][arow] = a0.w;
    As[ak+0][arow+64] = a1.x; As[ak+1][arow+64] = a1.y; As[ak+2][arow+64] = a1.z; As[ak+3][arow+64] = a1.w;
    *(float4*)&Bs[brow  ][bc] = b0;
    *(float4*)&Bs[brow+8][bc] = b1;
    __syncthreads();
    #pragma unroll
    for (int k = 0; k < 16; ++k){
      float av[8], bv[8];
      *(float4*)&av[0] = *(const float4*)&As[k][ty*8];
      *(float4*)&av[4] = *(const float4*)&As[k][ty*8+4];
      *(float4*)&bv[0] = *(const float4*)&Bs[k][tx*8];
      *(float4*)&bv[4] = *(const float4*)&Bs[k][tx*8+4];
      #pragma unroll
      for (int i = 0; i < 8; ++i)
        #pragma unroll
        for (int jj = 0; jj < 8; ++jj)
          acc[i][jj] = fmaf(av[i], bv[jj], acc[i][jj]);
    }
  }
  float bvals[8];
  *(float4*)&bvals[0] = *(const float4*)(bias + n0 + tx*8);
  *(float4*)&bvals[4] = *(const float4*)(bias + n0 + tx*8 + 4);
  float* Cp = Cc + (size_t)(m0 + ty*8)*1024 + n0 + tx*8;
  #pragma unroll
  for (int i = 0; i < 8; ++i){
    float4 o0 = make_float4(acc[i][0]+bvals[0], acc[i][1]+bvals[1], acc[i][2]+bvals[2], acc[i][3]+bvals[3]);
    float4 o1 = make_float4(acc[i][4]+bvals[4], acc[i][5]+bvals[5], acc[i][6]+bvals[6], acc[i][7]+bvals[7]);
    *(float4*)(Cp + (size_t)i*1024)     = o0;
    *(float4*)(Cp + (size_t)i*1024 + 4) = o1;
  }
}

// ---------------- LSTM recurrence: R5's PASSING kernel + spill fix ----------------
// 2 blocks per (batch,dir) chain; 512 threads own 512 gate rows as 2 half-rows x 128 k.
// DELTA vs R5: W split 24 float4-pairs in VGPRs (192 regs) + 8-float4-pair tail in LDS
// (wtail, stride 66 -> benign conflicts). launch_bounds(512,2) caps 256 VGPR -> no spill.
// FMA order identical to R5 -> bitwise-identical results. Exchange protocol unchanged.
__global__ __launch_bounds__(512, 2) void k_lstm2s(
    const float* __restrict__ xwF, const float* __restrict__ xwB,
    const float* __restrict__ whhf, const float* __restrict__ whhb,
    float* __restrict__ hout, int hBstride, int tOffF, int tOffB,
    int T, int epoch,
    float* __restrict__ hx, int* __restrict__ flags,
    float* __restrict__ hsave, float* __restrict__ csave)
{
  __shared__ float hfull[256];
  __shared__ float gls[512];
  __shared__ float wtail[512*66];       // 135 KB: per-thread 64-float W tail (q=24..31)
  const int blk = blockIdx.x;
  const int chain = blk >> 1;           // chain = b_local*2 + dir
  const int hh = blk & 1;
  const int b_local = chain >> 1;
  const int dir = chain & 1;
  const int t = threadIdx.x;
  const int wv = t >> 6, lane = t & 63;
  const int kap = lane >> 5, li = lane & 31;
  const int r0 = wv*64 + li*2;          // block-local rows r0, r0+1
  const int rK = r0 + kap;              // row this thread finalizes
  const int gateK = rK >> 7;
  float4 w0[24], w1[24];
  {
    const float* whh = dir ? whhb : whhf;
    const int g0 = r0 >> 7, i0 = r0 & 127;
    const float* a = whh + (size_t)(g0*256 + hh*128 + i0)*256 + kap*128;
    const float* b = a + 256;           // rowB = rowA + 1
    #pragma unroll
    for (int q = 0; q < 24; ++q){ w0[q] = *(const float4*)(a + q*4); w1[q] = *(const float4*)(b + q*4); }
    for (int q = 24; q < 32; ++q){
      #pragma unroll
      for (int e = 0; e < 4; ++e){
        wtail[t*66 + (q-24)*4 + e]      = a[q*4 + e];
        wtail[t*66 + 32 + (q-24)*4 + e] = b[q*4 + e];
      }
    }
  }
  if (t < 256) hfull[t] = hsave[chain*256 + t];
  float c = (t < 128) ? csave[chain*256 + hh*128 + t] : 0.f;
  __syncthreads();
  const int xcol = gateK*256 + hh*128 + (rK & 127);
  const float* xb = (dir ? xwB : xwF) + (size_t)b_local*T*1024 + xcol;
  float* hxme        = hx + (size_t)(chain*2 + hh)*256;        // [parity][128]
  const float* hxpt  = hx + (size_t)(chain*2 + (1-hh))*256;
  int* flg  = flags + chain*2 + hh;
  int* flgp = flags + chain*2 + (1-hh);
  const int tOff = dir ? tOffB : tOffF;
  float* hob = hout + (size_t)b_local*hBstride + dir*256 + hh*128;
  const float* wtb = &wtail[t*66];
  float xg = xb[(size_t)(dir ? (T-1) : 0)*1024];
  for (int s = 0; s < T; ++s){
    const int tt = dir ? (T-1-s) : s;
    float xn = 0.f;
    if (s < T-1) xn = xb[(size_t)(dir ? (T-2-s) : (s+1))*1024];   // prefetch
    float p0 = 0.f, p1 = 0.f;
    const float4* h4 = ((const float4*)hfull) + kap*32;
    #pragma unroll
    for (int q = 0; q < 24; ++q){
      float4 hv = h4[q];                        // wave-uniform addr -> LDS broadcast
      p0 = fmaf(w0[q].x, hv.x, p0);  p1 = fmaf(w1[q].x, hv.x, p1);
      p0 = fmaf(w0[q].y, hv.y, p0);  p1 = fmaf(w1[q].y, hv.y, p1);
      p0 = fmaf(w0[q].z, hv.z, p0);  p1 = fmaf(w1[q].z, hv.z, p1);
      p0 = fmaf(w0[q].w, hv.w, p0);  p1 = fmaf(w1[q].w, hv.w, p1);
    }
    #pragma unroll
    for (int q = 24; q < 32; ++q){              // LDS tail, same FMA order
      float4 hv = h4[q];
      const int o = (q-24)*4;
      p0 = fmaf(wtb[o+0], hv.x, p0);  p1 = fmaf(wtb[32+o+0], hv.x, p1);
      p0 = fmaf(wtb[o+1], hv.y, p0);  p1 = fmaf(wtb[32+o+1], hv.y, p1);
      p0 = fmaf(wtb[o+2], hv.z, p0);  p1 = fmaf(wtb[32+o+2], hv.z, p1);
      p0 = fmaf(wtb[o+3], hv.w, p0);  p1 = fmaf(wtb[32+o+3], hv.w, p1);
    }
    float q0 = p0 + __shfl_xor(p0, 32, 64);     // combine k-halves
    float q1 = p1 + __shfl_xor(p1, 32, 64);
    float acc = (kap ? q1 : q0) + xg;
    float act = (gateK == 2) ? tanhf(acc) : sigmf_(acc);   // i,f,o sigmoid; g tanh
    gls[rK] = act;
    __syncthreads();                            // B1: gates ready
    if (t < 128){
      c = gls[128 + t]*c + gls[t]*gls[256 + t];
      float h = gls[384 + t]*tanhf(c);
      hfull[hh*128 + t] = h;
      hxme[(s & 1)*128 + t] = h;                // publish (parity dbuf)
      hob[(size_t)(tOff + tt)*512 + t] = h;
    }
    __syncthreads();                            // B2: stores drained
    if (t == 0){
      __hip_atomic_store(flg, epoch + s + 1, __ATOMIC_RELEASE, __HIP_MEMORY_SCOPE_AGENT);
      int lim = 0;                              // bounded spin (hang fuse)
      while (__hip_atomic_load(flgp, __ATOMIC_ACQUIRE, __HIP_MEMORY_SCOPE_AGENT) < epoch + s + 1
             && ++lim < (1<<20)) {}
    }
    __syncthreads();                            // B3: partner data visible
    if (t < 128) hfull[(1 - hh)*128 + t] = hxpt[(s & 1)*128 + t];
    __syncthreads();                            // B4: hfull ready for next step
    xg = xn;
  }
  if (t < 128){
    hsave[chain*256 + hh*128 + t] = hfull[hh*128 + t];
    csave[chain*256 + hh*128 + t] = c;
  }
}

// ---------------- feats accumulation (one dir half per call; R5-proven) ----------------
__global__ __launch_bounds__(256) void k_feats_half(
    const float* __restrict__ h1s, const float* __restrict__ fcw, const float* __restrict__ fcb,
    float* __restrict__ feats, int b0, int logT, int Tm1, int tG0, int dir){
  int wv = threadIdx.x >> 6, lane = threadIdx.x & 63;
  int m = blockIdx.x*4 + wv;                 // m = bl*T + tl
  const float4* row = (const float4*)(h1s + (size_t)m*512 + dir*256);
  float4 rv = row[lane];
  int bl = m >> logT, tl = m & Tm1;
  size_t fbase = ((size_t)(b0 + bl)*512 + tG0 + tl)*11;
  #pragma unroll
  for (int n = 0; n < 11; ++n){
    const float4* wr = (const float4*)(fcw + n*512 + dir*256);
    float4 w4 = wr[lane];
    float p = rv.x*w4.x + rv.y*w4.y + rv.z*w4.z + rv.w*w4.w;
    #pragma unroll
    for (int off = 32; off > 0; off >>= 1) p += __shfl_down(p, off, 64);
    if (lane == 0){
      float add = (dir == 0) ? (p + fcb[n]) : p;
      feats[fbase + n] += add;
    }
  }
}

// ---------------- Viterbi: 1 wave per batch (R2/R5-proven) ----------------
__global__ __launch_bounds__(256) void k_viterbi(const float* __restrict__ feats,
                        const float* __restrict__ trans, float* __restrict__ out){
  __shared__ unsigned char bp[4][512][12];
  const int wave = threadIdx.x >> 6, lane = threadIdx.x & 63;
  const int b = blockIdx.x*4 + wave;
  const int j = lane;
  float tr[11];
  float fv;
  if (j < 11){
    #pragma unroll
    for (int p = 0; p < 11; ++p) tr[p] = trans[j*11 + p];
    fv = (j == 9) ? 0.f : -1000.f;
  } else {
    #pragma unroll
    for (int p = 0; p < 11; ++p) tr[p] = -1e30f;
    fv = -1e30f;
  }
  for (int t = 0; t < 512; ++t){
    float best = -1e38f; int bestp = 0;
    #pragma unroll
    for (int p = 0; p < 11; ++p){
      float v = __shfl(fv, p, 64) + tr[p];
      if (v > best){ best = v; bestp = p; }   // strict > keeps FIRST max (np.argmax)
    }
    float feat = (j < 11) ? feats[((size_t)b*512 + t)*11 + j] : 0.f;
    fv = best + feat;
    if (j < 11) bp[wave][t][j] = (unsigned char)bestp;
  }
  float term = (j < 11) ? fv + trans[10*11 + j] : -1e38f;
  float best = -1e38f; int bestp = 0;
  #pragma unroll
  for (int p = 0; p < 11; ++p){
    float v = __shfl(term, p, 64);
    if (v > best){ best = v; bestp = p; }
  }
  if (lane == 0){
    out[b] = best;
    float* path = out + 64 + (size_t)b*512;
    int cur = bestp;
    path[511] = (float)cur;
    for (int t = 511; t >= 1; --t){
      cur = bp[wave][t][cur];
      path[t-1] = (float)cur;
    }
  }
}

extern "C" void kernel_launch(void* const* d_in, const int* in_sizes, int n_in,
                              void* d_out, int out_size, void* d_ws, size_t ws_size,
                              hipStream_t stream){
  const int*   sent  = (const int*)d_in[0];
  const float* emb   = (const float*)d_in[2];
  const float* fcw   = (const float*)d_in[3];
  const float* fcb   = (const float*)d_in[4];
  const float* trans = (const float*)d_in[5];
  const float* wih0f = (const float*)d_in[6];
  const float* whh0f = (const float*)d_in[7];
  const float* b0f   = (const float*)d_in[8];
  const float* wih0b = (const float*)d_in[9];
  const float* whh0b = (const float*)d_in[10];
  const float* b0b   = (const float*)d_in[11];
  const float* wih1f = (const float*)d_in[12];
  const float* whh1f = (const float*)d_in[13];
  const float* b1f   = (const float*)d_in[14];
  const float* wih1b = (const float*)d_in[15];
  const float* whh1b = (const float*)d_in[16];
  const float* b1b   = (const float*)d_in[17];

  float* ws = (float*)d_ws;
  // -------- fixed region: R5's proven layout --------
  const size_t o_wT0f = 0;                         // 304*1024
  const size_t o_wT0b = o_wT0f + 311296;
  const size_t o_wT1f = o_wT0b + 311296;           // 512*1024
  const size_t o_wT1b = o_wT1f + 524288;
  const size_t o_hx   = o_wT1b + 524288;           // fp32 planes: 64*2 chains*2 hh*2 par*128 = 65536
  const size_t o_flag = o_hx   + 65536;            // 256 ints
  const size_t o_hs   = o_flag + 256;              // hsave 128 chains * 256 = 32768
  const size_t o_cs   = o_hs   + 32768;            // csave 32768
  const size_t o_feat = o_cs   + 32768;            // 32768*11 = 360448
  const size_t o_var  = o_feat + 360448;           // = 2,162,944 floats fixed (8.65 MB)
  float* wT0f = ws + o_wT0f;
  float* wT0b = ws + o_wT0b;
  float* wT1f = ws + o_wT1f;
  float* wT1b = ws + o_wT1b;
  float* hx    = ws + o_hx;
  int*   flags = (int*)(ws + o_flag);
  float* hsave = ws + o_hs;
  float* csave = ws + o_cs;
  float* feats = ws + o_feat;

  // -------- adaptive (C batches, T timesteps) slab sizing (R5 table + (8,64)) --------
  int C = 8, T = 32, logT = 5;
  {
    const int cc[8]  = {64, 64, 32, 32, 16, 16, 8, 8};
    const int tt[8]  = {32, 16, 32, 16, 32, 16, 64, 32};
    const int lt[8]  = { 5,  4,  5,  4,  5,  4,  6,  5};
    for (int i = 0; i < 8; ++i){
      size_t need = (o_var + (size_t)cc[i]*tt[i]*2656 + (size_t)cc[i]*262144)*4;
      if (need <= ws_size){ C = cc[i]; T = tt[i]; logT = lt[i]; break; }
    }
  }
  const int Tm1 = T - 1, S = 512 / T;
  float* XF  = ws + o_var;                        // [C*T,304]  (layer0)
  float* XB  = XF + (size_t)C*T*304;
  float* xwF = XB + (size_t)C*T*304;              // [C*T,1024]
  float* xwB = xwF + (size_t)C*T*1024;
  float* h0  = xwB + (size_t)C*T*1024;            // [C,512,512] fp32
  float* h1s = XF;                                // alias: [C,T,512] (layer1 slab)

  hipLaunchKernelGGL(k_prepw, dim3(512), dim3(256), 0, stream, wih0f, wT0f, 300, 304);
  hipLaunchKernelGGL(k_prepw, dim3(512), dim3(256), 0, stream, wih0b, wT0b, 300, 304);
  hipLaunchKernelGGL(k_prepw, dim3(512), dim3(256), 0, stream, wih1f, wT1f, 512, 512);
  hipLaunchKernelGGL(k_prepw, dim3(512), dim3(256), 0, stream, wih1b, wT1b, 512, 512);
  hipLaunchKernelGGL(k_zero,  dim3(512), dim3(256), 0, stream, feats, 360448);

  for (int b0 = 0; b0 < 64; b0 += C){
    for (int layer = 0; layer < 2; ++layer){
      // zero hx + flags + hsave + csave (contiguous region)
      hipLaunchKernelGGL(k_zero, dim3(256), dim3(256), 0, stream, ws + o_hx, 65536 + 256 + 65536);
      const float* whF = layer ? whh1f : whh0f;
      const float* whB = layer ? whh1b : whh0b;
      for (int sl = 0; sl < S; ++sl){
        const int sF = sl, sB = S - 1 - sl;
        const int M = C*T;
        if (layer == 0){
          int total = C*T*76;
          hipLaunchKernelGGL(k_gather, dim3((total+255)/256), dim3(256), 0, stream,
                             sent, emb, (float4*)XF, b0, sF*T, logT, Tm1, total);
          hipLaunchKernelGGL(k_gather, dim3((total+255)/256), dim3(256), 0, stream,
                             sent, emb, (float4*)XB, b0, sB*T, logT, Tm1, total);
          hipLaunchKernelGGL(k_gemm2, dim3(8, M/128, 2), dim3(256), 0, stream,
                             XF, XB, 304, 19, T, 0, 0, logT, Tm1,
                             wT0f, wT0b, b0f, b0b, xwF, xwB);
        } else {
          hipLaunchKernelGGL(k_gemm2, dim3(8, M/128, 2), dim3(256), 0, stream,
                             h0, h0, 512, 32, 512, sF*T, sB*T, logT, Tm1,
                             wT1f, wT1b, b1f, b1b, xwF, xwB);
        }
        {
          const float *xF = xwF, *xB = xwB, *wF = whF, *wB = whB;
          float* hop = layer ? h1s : h0;
          int hBs  = layer ? T*512 : 512*512;
          int tOF  = layer ? 0 : sF*T;
          int tOB  = layer ? 0 : sB*T;
          int Tk = T, ep = sl*T;
          float *hxp = hx, *hsp = hsave, *csp = csave; int *flp = flags;
          void* args[] = {(void*)&xF, (void*)&xB, (void*)&wF, (void*)&wB,
                          (void*)&hop, (void*)&hBs, (void*)&tOF, (void*)&tOB,
                          (void*)&Tk, (void*)&ep,
                          (void*)&hxp, (void*)&flp, (void*)&hsp, (void*)&csp};
          hipLaunchCooperativeKernel((const void*)k_lstm2s, dim3(C*4), dim3(512), args, 0, stream);
        }
        if (layer == 1){
          hipLaunchKernelGGL(k_feats_half, dim3(C*T/4), dim3(256), 0, stream,
                             h1s, fcw, fcb, feats, b0, logT, Tm1, sF*T, 0);
          hipLaunchKernelGGL(k_feats_half, dim3(C*T/4), dim3(256), 0, stream,
                             h1s, fcw, fcb, feats, b0, logT, Tm1, sB*T, 1);
        }
      }
    }
  }
  hipLaunchKernelGGL(k_viterbi, dim3(16), dim3(256), 0, stream, feats, trans, (float*)d_out);
}